// Round 8
// baseline (190.625 us; speedup 1.0000x reference)
//
#include <hip/hip_runtime.h>
#include <stdint.h>

// PressureLSTM: B=4096, T=512, F=32, H=32, gates=128 (i,f,g,o).
// Swapped-MFMA, permuted gate index pg = e*4 + gtype (verified r5-r7):
//   mfma_f32_16x16x32_bf16(A=W', B=X^T/H^T); lane's 4 acc regs = i,f,g,o of
//   (element e, batch row col) -> lane-local cell update.
// r8: 4 waves x 2 gate-tiles (wv, wv+4) per 16-row block. Same total MFMA/
//   VALU/trans issue per CU-step as r7, but the 8x-broadcast LDS B-fragment
//   reads drop to 4x (32KB -> 16KB per step-CU): LDS pipe was the serializer.
//   - x staging: 256 threads x float2 loads, packed-u32 LDS writes
//   - 4 independent MFMA chains/lane (2 tiles x {x-chain, h-chain}) for ILP
//   - fused-rcp activations (8 trans/cell), c clamped to +-16
// bf16x3 split (Whi*vhi + Whi*vlo + Wlo*vhi) ~ fp32 gate precision.

typedef __attribute__((ext_vector_type(8))) short short8;
typedef __attribute__((ext_vector_type(4))) float float4v;
typedef __attribute__((ext_vector_type(2))) float float2v;

#define T_LEN 512
#define B_ALL 4096
#define ROWS 16
#define NBLK (B_ALL / ROWS)   // 256 blocks -> 1 block/CU
#define P 40                  // shorts per LDS row (80 B)

static __device__ __forceinline__ void split_bf(float v, short* hi, short* lo) {
    // hi = truncated-bf16(v) (exact masked f32), lo = trunc-bf16(v - hi).
    uint32_t u = __float_as_uint(v);
    uint32_t uh = u & 0xFFFF0000u;
    float lof = v - __uint_as_float(uh);
    *hi = (short)(uh >> 16);
    *lo = (short)(__float_as_uint(lof) >> 16);
}
static __device__ __forceinline__ float bf2f(short s) {
    return __uint_as_float(((uint32_t)(uint16_t)s) << 16);
}
static __device__ __forceinline__ uint32_t pack2(short a, short b) {
    return (uint32_t)(uint16_t)a | ((uint32_t)(uint16_t)b << 16);
}

__global__ __launch_bounds__(256, 1) void lstm_fused_kernel(
    const float* __restrict__ x,     // [B, T, 32]
    const float* __restrict__ W_ih,  // [128, 32]
    const float* __restrict__ W_hh,  // [128, 32]
    const float* __restrict__ b_ih,  // [128]
    const float* __restrict__ b_hh,  // [128]
    const float* __restrict__ W_fc,  // [1, 32]
    const float* __restrict__ b_fc,  // [1]
    float* __restrict__ out)         // [B]
{
    const int tid  = threadIdx.x;    // 0..255
    const int wv   = tid >> 6;       // wave 0..3
    const int lane = tid & 63;
    const int col  = lane & 15;      // batch row within tile (all real)
    const int q    = lane >> 4;      // 0..3
    const int k0   = q * 8;
    const int b0   = blockIdx.x * ROWS;
    const int e0   = 4 * wv + q;     // tile-0 element (0..15)
    const int e1   = e0 + 16;        // tile-1 element (16..31)

    __shared__ __align__(16) short hs_hi[2][ROWS][P], hs_lo[2][ROWS][P];
    __shared__ __align__(16) short xs_hi[2][ROWS][P], xs_lo[2][ROWS][P];

    // ---- A-fragment weights for tiles tt0=wv, tt1=wv+4 (verified mapping):
    // lane holds W'[pg=16tt+col][k0..k0+7]; pg=e'*4+gt, e'=4tt+(col>>2), gt=col&3
    // pre-scale: i,f,o rows by -log2e (sigmoid via rcp(1+exp2)); g by +2*log2e.
    short8 wih_hi0, wih_lo0, whh_hi0, whh_lo0;
    short8 wih_hi1, wih_lo1, whh_hi1, whh_lo1;
    float4v bias0, bias1;
    {
        const int gt = col & 3;
        const float gs = (gt == 2) ? 2.88539008f : -1.44269504f;
        const int g0 = gt * 32 + (4 * wv + (col >> 2));        // tile wv
        const int g1 = gt * 32 + (4 * (wv + 4) + (col >> 2));  // tile wv+4
        const float* wr0 = W_ih + g0 * 32 + k0;
        const float* hr0 = W_hh + g0 * 32 + k0;
        const float* wr1 = W_ih + g1 * 32 + k0;
        const float* hr1 = W_hh + g1 * 32 + k0;
        #pragma unroll
        for (int i = 0; i < 8; ++i) {
            short h_, l_;
            split_bf(wr0[i] * gs, &h_, &l_); wih_hi0[i] = h_; wih_lo0[i] = l_;
            split_bf(hr0[i] * gs, &h_, &l_); whh_hi0[i] = h_; whh_lo0[i] = l_;
            split_bf(wr1[i] * gs, &h_, &l_); wih_hi1[i] = h_; wih_lo1[i] = l_;
            split_bf(hr1[i] * gs, &h_, &l_); whh_hi1[i] = h_; whh_lo1[i] = l_;
        }
        #pragma unroll
        for (int r = 0; r < 4; ++r) {
            const float gsr = (r == 2) ? 2.88539008f : -1.44269504f;
            bias0[r] = (b_ih[r * 32 + e0] + b_hh[r * 32 + e0]) * gsr;
            bias1[r] = (b_ih[r * 32 + e1] + b_hh[r * 32 + e1]) * gsr;
        }
    }

    float c0 = 0.f, c1 = 0.f;

    // ---- x staging: 256 threads cover 16 rows x 32 k; each owns (sr, k2..k2+1)
    const int sr = tid >> 4;          // staged row 0..15
    const int k2 = (tid & 15) << 1;   // staged k pair base (even)
    const float* xsrc = x + ((size_t)(b0 + sr) * T_LEN) * 32 + k2;

    float2v xA, xB;                   // x(t+1) [to convert], x(t+2) [in flight]
    {
        float2v v0 = *(const float2v*)(xsrc);
        short h0_, l0_, h1_, l1_;
        split_bf(v0[0], &h0_, &l0_);
        split_bf(v0[1], &h1_, &l1_);
        *(uint32_t*)&xs_hi[0][sr][k2] = pack2(h0_, h1_);
        *(uint32_t*)&xs_lo[0][sr][k2] = pack2(l0_, l1_);
        xA = *(const float2v*)(xsrc + 32);
        xB = *(const float2v*)(xsrc + 64);
        *(uint32_t*)&hs_hi[0][sr][k2] = 0u;   // h(-1) = 0
        *(uint32_t*)&hs_lo[0][sr][k2] = 0u;
    }
    __syncthreads();

    const float4v zero4 = {0.f, 0.f, 0.f, 0.f};

    // step t (parity PPAR=t&1): reads xs/hs[PPAR], writes xs/hs[PPAR^1].
    #define STEP(PPAR, XREG, TT)                                                 \
    {                                                                            \
        const short8 ax_hi = *(const short8*)&xs_hi[PPAR][col][k0];              \
        const short8 ax_lo = *(const short8*)&xs_lo[PPAR][col][k0];              \
        const short8 ah_hi = *(const short8*)&hs_hi[PPAR][col][k0];              \
        const short8 ah_lo = *(const short8*)&hs_lo[PPAR][col][k0];              \
        /* 4 independent chains: tile0/tile1 x x-chain/h-chain */                \
        float4v ax0 = bias0, ax1 = bias1, ahh0 = zero4, ahh1 = zero4;            \
        ax0  = __builtin_amdgcn_mfma_f32_16x16x32_bf16(wih_hi0, ax_hi, ax0, 0,0,0);  \
        ahh0 = __builtin_amdgcn_mfma_f32_16x16x32_bf16(whh_hi0, ah_hi, ahh0, 0,0,0); \
        ax1  = __builtin_amdgcn_mfma_f32_16x16x32_bf16(wih_hi1, ax_hi, ax1, 0,0,0);  \
        ahh1 = __builtin_amdgcn_mfma_f32_16x16x32_bf16(whh_hi1, ah_hi, ahh1, 0,0,0); \
        ax0  = __builtin_amdgcn_mfma_f32_16x16x32_bf16(wih_hi0, ax_lo, ax0, 0,0,0);  \
        ahh0 = __builtin_amdgcn_mfma_f32_16x16x32_bf16(whh_hi0, ah_lo, ahh0, 0,0,0); \
        ax1  = __builtin_amdgcn_mfma_f32_16x16x32_bf16(wih_hi1, ax_lo, ax1, 0,0,0);  \
        ahh1 = __builtin_amdgcn_mfma_f32_16x16x32_bf16(whh_hi1, ah_lo, ahh1, 0,0,0); \
        ax0  = __builtin_amdgcn_mfma_f32_16x16x32_bf16(wih_lo0, ax_hi, ax0, 0,0,0);  \
        ahh0 = __builtin_amdgcn_mfma_f32_16x16x32_bf16(whh_lo0, ah_hi, ahh0, 0,0,0); \
        ax1  = __builtin_amdgcn_mfma_f32_16x16x32_bf16(wih_lo1, ax_hi, ax1, 0,0,0);  \
        ahh1 = __builtin_amdgcn_mfma_f32_16x16x32_bf16(whh_lo1, ah_hi, ahh1, 0,0,0); \
        {   /* stage x(t+1) -> buffer PPAR^1 (fills MFMA shadow) */              \
            short h0_, l0_, h1_, l1_;                                            \
            split_bf(XREG[0], &h0_, &l0_);                                       \
            split_bf(XREG[1], &h1_, &l1_);                                       \
            *(uint32_t*)&xs_hi[PPAR ^ 1][sr][k2] = pack2(h0_, h1_);              \
            *(uint32_t*)&xs_lo[PPAR ^ 1][sr][k2] = pack2(l0_, l1_);              \
            int tn = (TT) + 3; if (tn >= T_LEN) tn = T_LEN - 1;                  \
            XREG = *(const float2v*)(xsrc + (size_t)tn * 32);                    \
        }                                                                        \
        const float4v g0 = ax0 + ahh0;                                           \
        const float4v g1 = ax1 + ahh1;                                           \
        /* cell 0 (element e0) */                                                \
        {                                                                        \
            const float Ai = __builtin_amdgcn_exp2f(g0[0]);                      \
            const float Af = __builtin_amdgcn_exp2f(g0[1]);                      \
            const float Bg = __builtin_amdgcn_exp2f(g0[2]);                      \
            const float Ao = __builtin_amdgcn_exp2f(g0[3]);                      \
            const float gf = __builtin_amdgcn_rcpf(1.0f + Af);                   \
            const float r1 = __builtin_amdgcn_rcpf((1.0f + Ai) * (1.0f + Bg));   \
            c0 = gf * c0 + (Bg - 1.0f) * r1;                                     \
            const float cc = fminf(fmaxf(c0, -16.0f), 16.0f);                    \
            const float C2 = __builtin_amdgcn_exp2f(cc * 2.88539008f);           \
            const float r3 = __builtin_amdgcn_rcpf((1.0f + Ao) * (1.0f + C2));   \
            const float hv = (C2 - 1.0f) * r3;                                   \
            short h_, l_;                                                        \
            split_bf(hv, &h_, &l_);                                              \
            hs_hi[PPAR ^ 1][col][e0] = h_;                                       \
            hs_lo[PPAR ^ 1][col][e0] = l_;                                       \
        }                                                                        \
        /* cell 1 (element e1) */                                                \
        {                                                                        \
            const float Ai = __builtin_amdgcn_exp2f(g1[0]);                      \
            const float Af = __builtin_amdgcn_exp2f(g1[1]);                      \
            const float Bg = __builtin_amdgcn_exp2f(g1[2]);                      \
            const float Ao = __builtin_amdgcn_exp2f(g1[3]);                      \
            const float gf = __builtin_amdgcn_rcpf(1.0f + Af);                   \
            const float r1 = __builtin_amdgcn_rcpf((1.0f + Ai) * (1.0f + Bg));   \
            c1 = gf * c1 + (Bg - 1.0f) * r1;                                     \
            const float cc = fminf(fmaxf(c1, -16.0f), 16.0f);                    \
            const float C2 = __builtin_amdgcn_exp2f(cc * 2.88539008f);           \
            const float r3 = __builtin_amdgcn_rcpf((1.0f + Ao) * (1.0f + C2));   \
            const float hv = (C2 - 1.0f) * r3;                                   \
            short h_, l_;                                                        \
            split_bf(hv, &h_, &l_);                                              \
            hs_hi[PPAR ^ 1][col][e1] = h_;                                       \
            hs_lo[PPAR ^ 1][col][e1] = l_;                                       \
        }                                                                        \
        __syncthreads();                                                         \
    }

    for (int t = 0; t < T_LEN; t += 2) {
        STEP(0, xA, t)
        STEP(1, xB, t + 1)
    }
    #undef STEP

    // ---- epilogue: h(511) was written to buffer 0 (step 511 has parity 1)
    if (tid < ROWS) {
        float s = b_fc[0];
        #pragma unroll
        for (int cc2 = 0; cc2 < 32; ++cc2) {
            float hvv = bf2f(hs_hi[0][tid][cc2]) + bf2f(hs_lo[0][tid][cc2]);
            s += hvv * W_fc[cc2];
        }
        out[b0 + tid] = s;
    }
}

extern "C" void kernel_launch(void* const* d_in, const int* in_sizes, int n_in,
                              void* d_out, int out_size, void* d_ws, size_t ws_size,
                              hipStream_t stream) {
    const float* x    = (const float*)d_in[0];
    const float* W_ih = (const float*)d_in[1];
    const float* W_hh = (const float*)d_in[2];
    const float* b_ih = (const float*)d_in[3];
    const float* b_hh = (const float*)d_in[4];
    const float* W_fc = (const float*)d_in[5];
    const float* b_fc = (const float*)d_in[6];
    float* out = (float*)d_out;

    lstm_fused_kernel<<<dim3(NBLK), dim3(256), 0, stream>>>(
        x, W_ih, W_hh, b_ih, b_hh, W_fc, b_fc, out);
}

// Round 9
// 148.429 us; speedup vs baseline: 1.2843x; 1.2843x over previous
//
#include <hip/hip_runtime.h>
#include <stdint.h>

// PressureLSTM: B=4096, T=512, F=32, H=32, gates=128 (i,f,g,o).
// Swapped-MFMA, permuted gate index pg = e*4 + gtype (verified r5-r8):
//   mfma(A=W', B=X^T/H^T); lane's 4 acc regs = i,f,g,o of
//   (element e=4*wv+q, batch row col) -> lane-local cell update.
// r9: back to r7 skeleton (8 waves x 1 tile; r8's 4-wave split regressed).
//   NEW: fp16x2 arithmetic replaces bf16x3.
//   - W split into f16 hi+lo (residual 2^-22); x,h stored as SINGLE f16
//     plane in LDS (rounding 2^-12). 4 MFMAs/step instead of 6; LDS ops
//     8 -> 4 per step; h-store is one v_cvt instead of 5-op split.
//   - two depth-2 parallel MFMA chains + one vector add (h-critical depth
//     3 -> 2): a1 = Wih_hi*x then Whh_lo*h; a2 = Whh_hi*h then Wih_lo*x.
//   - fused-rcp activations (8 trans/cell), c clamped to +-16, weights
//     pre-scaled by -log2e (i,f,o) / +2log2e (g).

typedef _Float16 half8 __attribute__((ext_vector_type(8)));
typedef __attribute__((ext_vector_type(4))) float float4v;

#define T_LEN 512
#define B_ALL 4096
#define ROWS 16
#define NBLK (B_ALL / ROWS)   // 256 blocks -> 1 block/CU
#define P 40                  // f16 per LDS row (80 B pitch: b128-aligned, 2-way-free banks)

__global__ __launch_bounds__(512, 2) void lstm_fused_kernel(
    const float* __restrict__ x,     // [B, T, 32]
    const float* __restrict__ W_ih,  // [128, 32]
    const float* __restrict__ W_hh,  // [128, 32]
    const float* __restrict__ b_ih,  // [128]
    const float* __restrict__ b_hh,  // [128]
    const float* __restrict__ W_fc,  // [1, 32]
    const float* __restrict__ b_fc,  // [1]
    float* __restrict__ out)         // [B]
{
    const int tid  = threadIdx.x;    // 0..511
    const int wv   = tid >> 6;       // wave 0..7 (gate tile wv)
    const int lane = tid & 63;
    const int col  = lane & 15;      // batch row within tile (all real)
    const int q    = lane >> 4;      // 0..3
    const int k0   = q * 8;
    const int b0   = blockIdx.x * ROWS;
    const int e    = 4 * wv + q;     // this lane's h element (0..31)

    __shared__ __align__(16) _Float16 hs[2][ROWS][P];
    __shared__ __align__(16) _Float16 xs[2][ROWS][P];

    // ---- A-fragment weights, f16 hi/lo split, pre-scaled per gate type:
    // lane holds W'[pg=16wv+col][k0..k0+7]; pg=e'*4+gt, e'=4wv+(col>>2), gt=col&3
    half8 wih_hi, wih_lo, whh_hi, whh_lo;
    {
        const int gt   = col & 3;
        const int gmem = gt * 32 + (4 * wv + (col >> 2));
        const float gs = (gt == 2) ? 2.88539008f : -1.44269504f;
        const float* wr = W_ih + gmem * 32 + k0;
        const float* hr = W_hh + gmem * 32 + k0;
        #pragma unroll
        for (int i = 0; i < 8; ++i) {
            float wvv = wr[i] * gs;
            _Float16 h_ = (_Float16)wvv;
            wih_hi[i] = h_;
            wih_lo[i] = (_Float16)(wvv - (float)h_);
            float hvv = hr[i] * gs;
            _Float16 g_ = (_Float16)hvv;
            whh_hi[i] = g_;
            whh_lo[i] = (_Float16)(hvv - (float)g_);
        }
    }
    // bias for acc reg r: gate type r of element e, same pre-scale
    float4v bias4;
    #pragma unroll
    for (int r = 0; r < 4; ++r) {
        const float gsr = (r == 2) ? 2.88539008f : -1.44269504f;
        bias4[r] = (b_ih[r * 32 + e] + b_hh[r * 32 + e]) * gsr;
    }

    float c = 0.f;

    // ---- x staging: all 512 threads cover 16 rows x 32 k, one dword each
    const int sr = tid >> 5;         // staged row 0..15
    const int sk = tid & 31;         // k element
    const float* xsrc = x + ((size_t)(b0 + sr) * T_LEN) * 32 + sk;

    float xA, xB;                    // x(t+1) [to convert], x(t+2) [in flight]
    {
        xs[0][sr][sk] = (_Float16)xsrc[0];   // x(0)
        xA = xsrc[32];                        // x(1)
        xB = xsrc[64];                        // x(2)
        hs[0][sr][sk] = (_Float16)0.f;        // h(-1) = 0
    }
    __syncthreads();

    const float4v zero4 = {0.f, 0.f, 0.f, 0.f};

    // step t (parity PPAR=t&1): reads xs/hs[PPAR], writes xs/hs[PPAR^1];
    // every thread converts XREG=x(t+1) and reloads XREG=x(t+3) (2-step slack).
    #define STEP(PPAR, XREG, TT)                                                \
    {                                                                           \
        const half8 ax = *(const half8*)&xs[PPAR][col][k0];                     \
        const half8 ah = *(const half8*)&hs[PPAR][col][k0];                     \
        /* two parallel depth-2 chains */                                       \
        float4v a1 = bias4, a2 = zero4;                                         \
        a1 = __builtin_amdgcn_mfma_f32_16x16x32_f16(wih_hi, ax, a1, 0, 0, 0);   \
        a2 = __builtin_amdgcn_mfma_f32_16x16x32_f16(whh_hi, ah, a2, 0, 0, 0);   \
        a1 = __builtin_amdgcn_mfma_f32_16x16x32_f16(whh_lo, ah, a1, 0, 0, 0);   \
        a2 = __builtin_amdgcn_mfma_f32_16x16x32_f16(wih_lo, ax, a2, 0, 0, 0);   \
        {   /* stage x(t+1) -> buffer PPAR^1 (fills MFMA shadow) */             \
            xs[PPAR ^ 1][sr][sk] = (_Float16)XREG;                              \
            int tn = (TT) + 3; if (tn >= T_LEN) tn = T_LEN - 1;                 \
            XREG = xsrc[(size_t)tn * 32];                                       \
        }                                                                       \
        const float4v g = a1 + a2;                                              \
        /* fused activations on pre-scaled pre-acts */                          \
        const float Ai = __builtin_amdgcn_exp2f(g[0]);                          \
        const float Af = __builtin_amdgcn_exp2f(g[1]);                          \
        const float Bg = __builtin_amdgcn_exp2f(g[2]);                          \
        const float Ao = __builtin_amdgcn_exp2f(g[3]);                          \
        const float gf = __builtin_amdgcn_rcpf(1.0f + Af);                      \
        const float r1 = __builtin_amdgcn_rcpf((1.0f + Ai) * (1.0f + Bg));      \
        c = gf * c + (Bg - 1.0f) * r1;                                          \
        const float cc = fminf(fmaxf(c, -16.0f), 16.0f);                        \
        const float C2 = __builtin_amdgcn_exp2f(cc * 2.88539008f);              \
        const float r3 = __builtin_amdgcn_rcpf((1.0f + Ao) * (1.0f + C2));     \
        const float hv = (C2 - 1.0f) * r3;                                      \
        hs[PPAR ^ 1][col][e] = (_Float16)hv;                                    \
        __syncthreads();                                                        \
    }

    for (int t = 0; t < T_LEN; t += 2) {
        STEP(0, xA, t)
        STEP(1, xB, t + 1)
    }
    #undef STEP

    // ---- epilogue: h(511) was written to buffer 0 (step 511 has parity 1)
    if (tid < ROWS) {
        float s = b_fc[0];
        #pragma unroll
        for (int cc2 = 0; cc2 < 32; ++cc2) {
            s += (float)hs[0][tid][cc2] * W_fc[cc2];
        }
        out[b0 + tid] = s;
    }
}

extern "C" void kernel_launch(void* const* d_in, const int* in_sizes, int n_in,
                              void* d_out, int out_size, void* d_ws, size_t ws_size,
                              hipStream_t stream) {
    const float* x    = (const float*)d_in[0];
    const float* W_ih = (const float*)d_in[1];
    const float* W_hh = (const float*)d_in[2];
    const float* b_ih = (const float*)d_in[3];
    const float* b_hh = (const float*)d_in[4];
    const float* W_fc = (const float*)d_in[5];
    const float* b_fc = (const float*)d_in[6];
    float* out = (float*)d_out;

    lstm_fused_kernel<<<dim3(NBLK), dim3(512), 0, stream>>>(
        x, W_ih, W_hh, b_ih, b_hh, W_fc, b_fc, out);
}

// Round 10
// 141.415 us; speedup vs baseline: 1.3480x; 1.0496x over previous
//
#include <hip/hip_runtime.h>
#include <stdint.h>

// PressureLSTM: B=4096, T=512, F=32, H=32, gates=128 (i,f,g,o).
// Swapped-MFMA, permuted gate index pg = e*4 + gtype (verified r5-r9):
//   mfma(A=W', B=X^T/H^T); lane's 4 acc regs = i,f,g,o of
//   (element e=4*wv+q, batch row col) -> lane-local cell update.
// r10 (from r9 skeleton: 8 waves x 1 tile, 16 real rows, 1 barrier/step):
//   - PURE f16 weights (RNE): 2 MFMAs/step (two parallel depth-1 chains
//     + vadd) instead of 4. r9's absmax was pinned at the output floor
//     through bf16x3 AND fp16x2 -> gate precision has slack for this.
//   - single-rcp fused c-update: 7 trans/cell instead of 8.
//   - x,h stored as single f16 plane in LDS; weights pre-scaled by
//     -log2e (i,f,o) / +2log2e (g) so activations are rcp/exp2 forms.

typedef _Float16 half8 __attribute__((ext_vector_type(8)));
typedef __attribute__((ext_vector_type(4))) float float4v;

#define T_LEN 512
#define B_ALL 4096
#define ROWS 16
#define NBLK (B_ALL / ROWS)   // 256 blocks -> 1 block/CU
#define P 40                  // f16 per LDS row (80 B pitch, b128-aligned)

__global__ __launch_bounds__(512, 2) void lstm_fused_kernel(
    const float* __restrict__ x,     // [B, T, 32]
    const float* __restrict__ W_ih,  // [128, 32]
    const float* __restrict__ W_hh,  // [128, 32]
    const float* __restrict__ b_ih,  // [128]
    const float* __restrict__ b_hh,  // [128]
    const float* __restrict__ W_fc,  // [1, 32]
    const float* __restrict__ b_fc,  // [1]
    float* __restrict__ out)         // [B]
{
    const int tid  = threadIdx.x;    // 0..511
    const int wv   = tid >> 6;       // wave 0..7 (gate tile wv)
    const int lane = tid & 63;
    const int col  = lane & 15;      // batch row within tile (all real)
    const int q    = lane >> 4;      // 0..3
    const int k0   = q * 8;
    const int b0   = blockIdx.x * ROWS;
    const int e    = 4 * wv + q;     // this lane's h element (0..31)

    __shared__ __align__(16) _Float16 hs[2][ROWS][P];
    __shared__ __align__(16) _Float16 xs[2][ROWS][P];

    // ---- A-fragment weights, single f16 (RNE), pre-scaled per gate type:
    // lane holds W'[pg=16wv+col][k0..k0+7]; pg=e'*4+gt, e'=4wv+(col>>2), gt=col&3
    half8 wih, whh;
    {
        const int gt   = col & 3;
        const int gmem = gt * 32 + (4 * wv + (col >> 2));
        const float gs = (gt == 2) ? 2.88539008f : -1.44269504f;
        const float* wr = W_ih + gmem * 32 + k0;
        const float* hr = W_hh + gmem * 32 + k0;
        #pragma unroll
        for (int i = 0; i < 8; ++i) {
            wih[i] = (_Float16)(wr[i] * gs);
            whh[i] = (_Float16)(hr[i] * gs);
        }
    }
    // bias for acc reg r: gate type r of element e, same pre-scale
    float4v bias4;
    #pragma unroll
    for (int r = 0; r < 4; ++r) {
        const float gsr = (r == 2) ? 2.88539008f : -1.44269504f;
        bias4[r] = (b_ih[r * 32 + e] + b_hh[r * 32 + e]) * gsr;
    }

    float c = 0.f;

    // ---- x staging: all 512 threads cover 16 rows x 32 k, one dword each
    const int sr = tid >> 5;         // staged row 0..15
    const int sk = tid & 31;         // k element
    const float* xsrc = x + ((size_t)(b0 + sr) * T_LEN) * 32 + sk;

    float xA, xB;                    // x(t+1) [to convert], x(t+2) [in flight]
    {
        xs[0][sr][sk] = (_Float16)xsrc[0];   // x(0)
        xA = xsrc[32];                        // x(1)
        xB = xsrc[64];                        // x(2)
        hs[0][sr][sk] = (_Float16)0.f;        // h(-1) = 0
    }
    __syncthreads();

    const float4v zero4 = {0.f, 0.f, 0.f, 0.f};

    // step t (parity PPAR=t&1): reads xs/hs[PPAR], writes xs/hs[PPAR^1];
    // every thread converts XREG=x(t+1) and reloads XREG=x(t+3) (2-step slack).
    #define STEP(PPAR, XREG, TT)                                                \
    {                                                                           \
        const half8 ax = *(const half8*)&xs[PPAR][col][k0];                     \
        const half8 ah = *(const half8*)&hs[PPAR][col][k0];                     \
        /* two parallel depth-1 chains */                                       \
        float4v a1 = bias4, a2 = zero4;                                         \
        a1 = __builtin_amdgcn_mfma_f32_16x16x32_f16(wih, ax, a1, 0, 0, 0);      \
        a2 = __builtin_amdgcn_mfma_f32_16x16x32_f16(whh, ah, a2, 0, 0, 0);      \
        {   /* stage x(t+1) -> buffer PPAR^1 (fills MFMA shadow) */             \
            xs[PPAR ^ 1][sr][sk] = (_Float16)XREG;                              \
            int tn = (TT) + 3; if (tn >= T_LEN) tn = T_LEN - 1;                 \
            XREG = xsrc[(size_t)tn * 32];                                       \
        }                                                                       \
        const float4v g = a1 + a2;                                              \
        /* fused activations on pre-scaled pre-acts (single-rcp c-update):   */ \
        /* c' = [c(1+Ai)(1+Bg) + (Bg-1)(1+Af)] * rcp((1+Af)(1+Ai)(1+Bg))    */  \
        const float Ai = __builtin_amdgcn_exp2f(g[0]);                          \
        const float Af = __builtin_amdgcn_exp2f(g[1]);                          \
        const float Bg = __builtin_amdgcn_exp2f(g[2]);                          \
        const float Ao = __builtin_amdgcn_exp2f(g[3]);                          \
        const float pI = 1.0f + Ai;                                             \
        const float pG = 1.0f + Bg;                                             \
        const float pF = 1.0f + Af;                                             \
        const float pIG = pI * pG;                                              \
        const float num = c * pIG + (Bg - 1.0f) * pF;                           \
        c = num * __builtin_amdgcn_rcpf(pF * pIG);                              \
        const float cc = fminf(fmaxf(c, -16.0f), 16.0f);                        \
        const float C2 = __builtin_amdgcn_exp2f(cc * 2.88539008f);              \
        const float r3 = __builtin_amdgcn_rcpf((1.0f + Ao) * (1.0f + C2));      \
        const float hv = (C2 - 1.0f) * r3;                                      \
        hs[PPAR ^ 1][col][e] = (_Float16)hv;                                    \
        __syncthreads();                                                        \
    }

    for (int t = 0; t < T_LEN; t += 2) {
        STEP(0, xA, t)
        STEP(1, xB, t + 1)
    }
    #undef STEP

    // ---- epilogue: h(511) was written to buffer 0 (step 511 has parity 1)
    if (tid < ROWS) {
        float s = b_fc[0];
        #pragma unroll
        for (int cc2 = 0; cc2 < 32; ++cc2) {
            s += (float)hs[0][tid][cc2] * W_fc[cc2];
        }
        out[b0 + tid] = s;
    }
}

extern "C" void kernel_launch(void* const* d_in, const int* in_sizes, int n_in,
                              void* d_out, int out_size, void* d_ws, size_t ws_size,
                              hipStream_t stream) {
    const float* x    = (const float*)d_in[0];
    const float* W_ih = (const float*)d_in[1];
    const float* W_hh = (const float*)d_in[2];
    const float* b_ih = (const float*)d_in[3];
    const float* b_hh = (const float*)d_in[4];
    const float* W_fc = (const float*)d_in[5];
    const float* b_fc = (const float*)d_in[6];
    float* out = (float*)d_out;

    lstm_fused_kernel<<<dim3(NBLK), dim3(512), 0, stream>>>(
        x, W_ih, W_hh, b_ih, b_hh, W_fc, b_fc, out);
}

// Round 11
// 137.150 us; speedup vs baseline: 1.3899x; 1.0311x over previous
//
#include <hip/hip_runtime.h>
#include <stdint.h>

// PressureLSTM: B=4096, T=512, F=32, H=32, gates=128 (i,f,g,o).
// Swapped-MFMA, permuted gate index pg = e*4 + gtype (verified r5-r10):
//   mfma(A=W', B=X^T/H^T); lane's 4 acc regs = i,f,g,o of
//   (element e=4*wv+q, batch row col) -> lane-local cell update.
// r11 (from r10: 8 waves, 16 rows, f16 weights, 1 barrier/step):
//   CRITICAL-PATH SURGERY: x-side hoisted one step ahead.
//   - xs is a 4-buffer ring staged 3 steps ahead; during step t we pre-read
//     ax(t+1) and pre-compute a1c = mfma(wih, ax(t+1), bias) in the shadow
//     of step t's activations.
//   - critical MFMA: acc = mfma(whh, ah, C=a1c) -- x-projection enters as
//     the C operand: no second critical ds_read (LDS returns in-order, so
//     the ah wait doesn't cover the later ax read) and no a1+a2 vadd.
//   - post-barrier chain: ds_read(ah) -> 1 MFMA -> activations -> write.
//   - single-rcp fused c-update (7 trans/cell), c clamped to +-16, weights
//     pre-scaled by -log2e (i,f,o) / +2log2e (g).

typedef _Float16 half8 __attribute__((ext_vector_type(8)));
typedef __attribute__((ext_vector_type(4))) float float4v;

#define T_LEN 512
#define B_ALL 4096
#define ROWS 16
#define NBLK (B_ALL / ROWS)   // 256 blocks -> 1 block/CU
#define P 40                  // f16 per LDS row (80 B pitch, b128-aligned)

__global__ __launch_bounds__(512, 2) void lstm_fused_kernel(
    const float* __restrict__ x,     // [B, T, 32]
    const float* __restrict__ W_ih,  // [128, 32]
    const float* __restrict__ W_hh,  // [128, 32]
    const float* __restrict__ b_ih,  // [128]
    const float* __restrict__ b_hh,  // [128]
    const float* __restrict__ W_fc,  // [1, 32]
    const float* __restrict__ b_fc,  // [1]
    float* __restrict__ out)         // [B]
{
    const int tid  = threadIdx.x;    // 0..511
    const int wv   = tid >> 6;       // wave 0..7 (gate tile wv)
    const int lane = tid & 63;
    const int col  = lane & 15;      // batch row within tile (all real)
    const int q    = lane >> 4;      // 0..3
    const int k0   = q * 8;
    const int b0   = blockIdx.x * ROWS;
    const int e    = 4 * wv + q;     // this lane's h element (0..31)

    __shared__ __align__(16) _Float16 hs[2][ROWS][P];
    __shared__ __align__(16) _Float16 xs[4][ROWS][P];

    // ---- A-fragment weights, single f16 (RNE), pre-scaled per gate type:
    // lane holds W'[pg=16wv+col][k0..k0+7]; pg=e'*4+gt, e'=4wv+(col>>2), gt=col&3
    half8 wih, whh;
    {
        const int gt   = col & 3;
        const int gmem = gt * 32 + (4 * wv + (col >> 2));
        const float gs = (gt == 2) ? 2.88539008f : -1.44269504f;
        const float* wr = W_ih + gmem * 32 + k0;
        const float* hr = W_hh + gmem * 32 + k0;
        #pragma unroll
        for (int i = 0; i < 8; ++i) {
            wih[i] = (_Float16)(wr[i] * gs);
            whh[i] = (_Float16)(hr[i] * gs);
        }
    }
    // bias for acc reg r: gate type r of element e, same pre-scale
    float4v bias4;
    #pragma unroll
    for (int r = 0; r < 4; ++r) {
        const float gsr = (r == 2) ? 2.88539008f : -1.44269504f;
        bias4[r] = (b_ih[r * 32 + e] + b_hh[r * 32 + e]) * gsr;
    }

    float c = 0.f;

    // ---- x staging: all 512 threads cover 16 rows x 32 k, one value each
    const int sr = tid >> 5;         // staged row 0..15
    const int sk = tid & 31;         // k element
    const float* xsrc = x + ((size_t)(b0 + sr) * T_LEN) * 32 + sk;

    // prologue: prime xs[0..2] with x(0..2); h(-1)=0; xA=x(3), xB=x(4)
    float xA, xB;
    {
        xs[0][sr][sk] = (_Float16)xsrc[0];
        xs[1][sr][sk] = (_Float16)xsrc[32];
        xs[2][sr][sk] = (_Float16)xsrc[64];
        hs[0][sr][sk] = (_Float16)0.f;
        xA = xsrc[3 * 32];
        xB = xsrc[4 * 32];
    }
    __syncthreads();

    // a1c for t=0 (x-side acc, bias folded)
    float4v a1c;
    {
        const half8 ax0 = *(const half8*)&xs[0][col][k0];
        a1c = __builtin_amdgcn_mfma_f32_16x16x32_f16(wih, ax0, bias4, 0, 0, 0);
    }

    // step t (hs parity p=t&1): reads hs[p] (critical) + xs[(t+1)&3] (next x);
    // stages x(t+3) (held in XREG) -> xs[(t+3)&3]; reloads XREG = x(t+5).
    #define STEP(PPAR, XREG, TT)                                                \
    {                                                                           \
        const int xq = ((TT) + 1) & 3;                                          \
        const int xw = ((TT) + 3) & 3;                                          \
        const half8 ah  = *(const half8*)&hs[PPAR][col][k0];  /* critical */    \
        const half8 axn = *(const half8*)&xs[xq][col][k0];    /* next-step x */ \
        /* critical MFMA: x-projection enters as C operand */                   \
        const float4v acc =                                                     \
            __builtin_amdgcn_mfma_f32_16x16x32_f16(whh, ah, a1c, 0, 0, 0);      \
        /* next step's x-side acc (off critical path) */                        \
        a1c = __builtin_amdgcn_mfma_f32_16x16x32_f16(wih, axn, bias4, 0, 0, 0); \
        {   /* stage x(TT+3) -> xs[xw]; reload XREG = x(TT+5) */                \
            xs[xw][sr][sk] = (_Float16)XREG;                                    \
            int tn = (TT) + 5; if (tn >= T_LEN) tn = T_LEN - 1;                 \
            XREG = xsrc[(size_t)tn * 32];                                       \
        }                                                                       \
        /* fused activations on pre-scaled pre-acts (single-rcp c-update):   */ \
        /* c' = [c(1+Ai)(1+Bg) + (Bg-1)(1+Af)] * rcp((1+Af)(1+Ai)(1+Bg))    */  \
        const float Ai = __builtin_amdgcn_exp2f(acc[0]);                        \
        const float Af = __builtin_amdgcn_exp2f(acc[1]);                        \
        const float Bg = __builtin_amdgcn_exp2f(acc[2]);                        \
        const float Ao = __builtin_amdgcn_exp2f(acc[3]);                        \
        const float pI = 1.0f + Ai;                                             \
        const float pG = 1.0f + Bg;                                             \
        const float pF = 1.0f + Af;                                             \
        const float pIG = pI * pG;                                              \
        const float num = c * pIG + (Bg - 1.0f) * pF;                           \
        c = num * __builtin_amdgcn_rcpf(pF * pIG);                              \
        const float cc = fminf(fmaxf(c, -16.0f), 16.0f);                        \
        const float C2 = __builtin_amdgcn_exp2f(cc * 2.88539008f);              \
        const float r3 = __builtin_amdgcn_rcpf((1.0f + Ao) * (1.0f + C2));      \
        const float hv = (C2 - 1.0f) * r3;                                      \
        hs[PPAR ^ 1][col][e] = (_Float16)hv;                                    \
        __syncthreads();                                                        \
    }

    for (int t = 0; t < T_LEN; t += 2) {
        STEP(0, xA, t)
        STEP(1, xB, t + 1)
    }
    #undef STEP

    // ---- epilogue: h(511) was written to hs[0] (step 511 has parity 1)
    if (tid < ROWS) {
        float s = b_fc[0];
        #pragma unroll
        for (int cc2 = 0; cc2 < 32; ++cc2) {
            s += (float)hs[0][tid][cc2] * W_fc[cc2];
        }
        out[b0 + tid] = s;
    }
}

extern "C" void kernel_launch(void* const* d_in, const int* in_sizes, int n_in,
                              void* d_out, int out_size, void* d_ws, size_t ws_size,
                              hipStream_t stream) {
    const float* x    = (const float*)d_in[0];
    const float* W_ih = (const float*)d_in[1];
    const float* W_hh = (const float*)d_in[2];
    const float* b_ih = (const float*)d_in[3];
    const float* b_hh = (const float*)d_in[4];
    const float* W_fc = (const float*)d_in[5];
    const float* b_fc = (const float*)d_in[6];
    float* out = (float*)d_out;

    lstm_fused_kernel<<<dim3(NBLK), dim3(512), 0, stream>>>(
        x, W_ih, W_hh, b_ih, b_hh, W_fc, b_fc, out);
}